// Round 1
// baseline (59.470 us; speedup 1.0000x reference)
//
#include <hip/hip_runtime.h>

#define PS   25
#define PAD  12
#define EPSV (1.0f / 255.0f)
#define WID  512
#define HEI  512
#define NB   16
#define CH   3

__device__ __forceinline__ int reflect_idx(int i, int n) {
    // single reflection is sufficient since PAD < n
    if (i < 0)  i = -i;
    if (i >= n) i = 2 * n - 2 - i;
    return i;
}

// Kernel A: per-pixel channel stats + horizontal 25-tap reflect box-sum.
// Writes mh (sum of channel-mean), sh (sum of channel-mean-of-squares) to ws,
// and saturation to out (kernel C reads it back before overwriting).
__global__ __launch_bounds__(256)
void kernA(const float* __restrict__ img,
           float* __restrict__ mh,
           float* __restrict__ sh,
           float* __restrict__ sat)
{
    const int seg = blockIdx.x;      // 0..1  (512 / 256)
    const int y   = blockIdx.y;      // 0..511
    const int b   = blockIdx.z;      // 0..15
    const int t   = threadIdx.x;     // 0..255
    const int x0  = seg * 256;

    __shared__ float sm[256 + 2 * PAD];
    __shared__ float ss[256 + 2 * PAD];

    const size_t plane = (size_t)HEI * WID;
    const float* base = img + (size_t)b * CH * plane + (size_t)y * WID;

    // cooperative halo load: 280 columns
    for (int i = t; i < 256 + 2 * PAD; i += 256) {
        int x = reflect_idx(x0 - PAD + i, WID);
        float r  = base[x];
        float g  = base[plane + x];
        float bl = base[2 * plane + x];
        sm[i] = (r + g + bl) * (1.0f / 3.0f);
        ss[i] = (r * r + g * g + bl * bl) * (1.0f / 3.0f);
    }
    __syncthreads();

    float msum = 0.f, ssum = 0.f;
#pragma unroll
    for (int k = 0; k < PS; ++k) {
        msum += sm[t + k];
        ssum += ss[t + k];
    }

    const size_t oidx = ((size_t)b * HEI + y) * WID + x0 + t;
    mh[oidx] = msum;
    sh[oidx] = ssum;

    // saturation for this thread's own pixel (loads are L1-warm from halo load)
    {
        int x = x0 + t;
        float r  = base[x];
        float g  = base[plane + x];
        float bl = base[2 * plane + x];
        float mx = fmaxf(r, fmaxf(g, bl));
        float mn = fminf(r, fminf(g, bl));
        sat[oidx] = (mx - mn + EPSV) / (mx + EPSV);
    }
}

// Kernel C: vertical 25-tap reflect box-sum + final score.
__global__ __launch_bounds__(256)
void kernC(const float* __restrict__ mh,
           const float* __restrict__ sh,
           float* __restrict__ out)
{
    const size_t gid = (size_t)blockIdx.x * 256 + threadIdx.x;
    const int b   = (int)(gid >> 18);        // H*W = 2^18
    const int rem = (int)(gid & 262143);
    const int y   = rem >> 9;                // W = 2^9
    const int x   = rem & 511;

    const float* mb = mh + ((size_t)b << 18);
    const float* sb = sh + ((size_t)b << 18);

    float msum = 0.f, ssum = 0.f;
#pragma unroll
    for (int k = 0; k < PS; ++k) {
        int ry = reflect_idx(y - PAD + k, HEI);
        msum += mb[((size_t)ry << 9) + x];
        ssum += sb[((size_t)ry << 9) + x];
    }

    const float inv = 1.0f / (float)(PS * PS);
    float mean     = msum * inv;
    float msq      = ssum * inv;
    float contrast = msq - mean * mean;
    float exposed  = fabsf(mean - 0.5f) + EPSV;

    float s = out[gid];                      // saturation written by kernA
    out[gid] = s * contrast / exposed;
}

extern "C" void kernel_launch(void* const* d_in, const int* in_sizes, int n_in,
                              void* d_out, int out_size, void* d_ws, size_t ws_size,
                              hipStream_t stream)
{
    const float* img = (const float*)d_in[0];
    float* out = (float*)d_out;

    const size_t plane_elems = (size_t)NB * HEI * WID;   // 4 Mi elements
    float* mh = (float*)d_ws;
    float* sh = mh + plane_elems;

    dim3 gridA(WID / 256, HEI, NB);
    kernA<<<gridA, 256, 0, stream>>>(img, mh, sh, out);

    const int nblocksC = (int)(plane_elems / 256);
    kernC<<<nblocksC, 256, 0, stream>>>(mh, sh, out);
}

// Round 2
// 44.231 us; speedup vs baseline: 1.3445x; 1.3445x over previous
//
#include <hip/hip_runtime.h>

#define PS   25
#define PAD  12
#define EPSV (1.0f / 255.0f)
#define WID  512
#define HEI  512
#define NB   16

#define TW   64            // output tile width
#define TH   32            // output tile height
#define IW   (TW + 2*PAD)  // 88
#define IH   (TH + 2*PAD)  // 56
#define IWP  89            // padded LDS stride (odd -> conflict-free columns)
#define SATP 65            // padded sat stride

__device__ __forceinline__ int reflect_idx(int i, int n) {
    if (i < 0)  i = -i;
    if (i >= n) i = 2 * n - 2 - i;
    return i;
}

__global__ __launch_bounds__(256, 2)
void fused_score(const float* __restrict__ img, float* __restrict__ out)
{
    const int t  = threadIdx.x;
    const int x0 = blockIdx.x * TW;     // 0..448
    const int y0 = blockIdx.y * TH;     // 0..480
    const int b  = blockIdx.z;

    __shared__ float smM[IH][IWP];      // channel-mean
    __shared__ float smS[IH][IWP];      // channel-mean of squares
    __shared__ float vM[TH][IWP];       // vertical 25-tap sums
    __shared__ float vS[TH][IWP];
    __shared__ float smSat[TH][SATP];   // saturation of output pixels

    const size_t plane = (size_t)HEI * WID;
    const float* base = img + (size_t)b * 3 * plane;

    // ---- stage 1: load halo region, compute m, s (and sat for interior) ----
    for (int i = t; i < IH * IW; i += 256) {
        int iy = i / IW;
        int ix = i - iy * IW;
        int gy = reflect_idx(y0 - PAD + iy, HEI);
        int gx = reflect_idx(x0 - PAD + ix, WID);
        size_t idx = (size_t)gy * WID + gx;
        float r  = base[idx];
        float g  = base[plane + idx];
        float bl = base[2 * plane + idx];
        smM[iy][ix] = (r + g + bl) * (1.0f / 3.0f);
        smS[iy][ix] = fmaf(r, r, fmaf(g, g, bl * bl)) * (1.0f / 3.0f);
        if (iy >= PAD && iy < PAD + TH && ix >= PAD && ix < PAD + TW) {
            float mx = fmaxf(r, fmaxf(g, bl));
            float mn = fminf(r, fminf(g, bl));
            smSat[iy - PAD][ix - PAD] = (mx - mn + EPSV) / (mx + EPSV);
        }
    }
    __syncthreads();

    // ---- stage 2: vertical 25-tap running sum (tasks: 2*IW = 176) ----
    if (t < 2 * IW) {
        const int x = (t < IW) ? t : t - IW;
        const float (*src)[IWP] = (t < IW) ? smM : smS;
        float (*dst)[IWP] = (t < IW) ? vM : vS;
        float sum = 0.f;
#pragma unroll
        for (int k = 0; k < PS; ++k) sum += src[k][x];
        dst[0][x] = sum;
        for (int y = 1; y < TH; ++y) {
            sum += src[y + PS - 1][x] - src[y - 1][x];
            dst[y][x] = sum;
        }
    }
    __syncthreads();

    // ---- stage 3: horizontal 25-tap running sums + final score ----
    // tasks: TH rows x 4 segments of 16 = 128
    if (t < TH * 4) {
        const int y  = t >> 2;
        const int sx = (t & 3) * 16;
        float msum = 0.f, ssum = 0.f;
#pragma unroll
        for (int k = 0; k < PS; ++k) {
            msum += vM[y][sx + k];
            ssum += vS[y][sx + k];
        }
        float* orow = out + ((size_t)b * HEI + (y0 + y)) * WID + x0 + sx;
        const float inv = 1.0f / (float)(PS * PS);
#pragma unroll
        for (int j = 0; j < 16; ++j) {
            float mean     = msum * inv;
            float msq      = ssum * inv;
            float contrast = msq - mean * mean;
            float exposed  = fabsf(mean - 0.5f) + EPSV;
            orow[j] = smSat[y][sx + j] * contrast / exposed;
            if (j < 15) {
                msum += vM[y][sx + j + PS] - vM[y][sx + j];
                ssum += vS[y][sx + j + PS] - vS[y][sx + j];
            }
        }
    }
}

extern "C" void kernel_launch(void* const* d_in, const int* in_sizes, int n_in,
                              void* d_out, int out_size, void* d_ws, size_t ws_size,
                              hipStream_t stream)
{
    const float* img = (const float*)d_in[0];
    float* out = (float*)d_out;

    dim3 grid(WID / TW, HEI / TH, NB);
    fused_score<<<grid, 256, 0, stream>>>(img, out);
}